// Round 2
// baseline (799.529 us; speedup 1.0000x reference)
//
#include <hip/hip_runtime.h>
#include <math.h>

// Problem constants
#define NTHREADS 256
#define TROWS 16            // rows (tokens) per block
#define TOKN 13824          // 24*24*24
#define MASKN 10368         // 0.75 * TOKN
#define UNMASKN 3456        // TOKN - MASKN
#define EMB 768
#define NPOS 24
#define NBATCH 4
#define ABLOCKS (TOKN / TROWS)    // 864 blocks for unmask rows (4 batches * 3456 rows)
#define BBLOCKS (MASKN / TROWS)   // 648 blocks for mask rows (computed once, stored x4)
#define TABN (NPOS * 256)         // 6144 floats = 24 KB in d_ws

// Setup: build sincos pos-enc table in d_ws + write mask_idx output.
__global__ __launch_bounds__(NTHREADS) void setup_kernel(
    const int* __restrict__ perm, float* __restrict__ tabg,
    float* __restrict__ out_idx)
{
  int i = blockIdx.x * NTHREADS + threadIdx.x;
  if (i < MASKN) out_idx[i] = (float)perm[i];
  if (i < TABN) {
    // inv_freq[j] = 10000^(-j/128) = 2^(-j * log2(10000)/128)
    const float c0 = 13.287712379549449f / 128.0f;
    int pos = i >> 8, e = i & 255, j = e >> 1;
    float s = (float)pos * exp2f(-(float)j * c0);
    tabg[i] = (e & 1) ? cosf(s) : sinf(s);
  }
}

__global__ __launch_bounds__(NTHREADS, 4) void fused_embed_ln(
    const float* __restrict__ x, const float* __restrict__ W,
    const float* __restrict__ pb, const float* __restrict__ mt,
    const float* __restrict__ gmm, const float* __restrict__ bta,
    const int* __restrict__ perm, const float* __restrict__ tabg,
    float* __restrict__ out)
{
  __shared__ __align__(16) float patch[TROWS * 64];  // 4 KB staged patch rows
  __shared__ float wred[TROWS][4][2];
  __shared__ float rowstat[TROWS][2];
  __shared__ int tok[TROWS];
  __shared__ int h256[TROWS], w256[TROWS], d256[TROWS]; // pos-enc table offsets

  const int tid = threadIdx.x;
  const int blk = blockIdx.x;
  const bool isA = blk < ABLOCKS;

  // --- token indices + decomposed positions for this block's rows ---
  if (tid < TROWS) {
    int r;
    if (isA) {
      int row0 = blk * TROWS;            // global unmask row in [0, 13824)
      int u = row0 % UNMASKN + tid;      // 3456 % 16 == 0 -> block stays in one batch
      r = perm[MASKN + u];               // unmask_idx[u]
    } else {
      int m0 = (blk - ABLOCKS) * TROWS;
      r = perm[m0 + tid];                // mask_idx[m]
    }
    tok[tid] = r;
    int h = r / 576; int rem = r - h * 576;
    int w = rem / 24; int d = rem - w * 24;
    h256[tid] = h << 8; w256[tid] = w << 8; d256[tid] = d << 8;
  }
  __syncthreads();

  // --- stage 16 patch rows (64 floats each) into LDS ---
  if (isA) {
    int b = (blk * TROWS) / UNMASKN;
    {
      int i = tid;                         // 256 = TROWS*16 float4 segments
      int t = i >> 4, seg = i & 15;        // seg = ph*4 + pw; float4 covers pd 0..3
      int h = h256[t] >> 8, w = w256[t] >> 8, d = d256[t] >> 8;
      int ph = seg >> 2, pw = seg & 3;
      const float4* src = (const float4*)(x +
          ((((long)b * 96 + h * 4 + ph) * 96 + (w * 4 + pw)) * 96 + d * 4));
      ((float4*)patch)[i] = *src;
    }
  } else {
    int m0 = (blk - ABLOCKS) * TROWS;
    const float4* src = (const float4*)(mt + (long)m0 * 64);
    ((float4*)patch)[tid] = src[tid];
  }
  __syncthreads();

  // --- GEMM: each thread accumulates columns {tid, tid+256, tid+512} for 16 rows ---
  float a0[TROWS], a1[TROWS], a2[TROWS];
  #pragma unroll
  for (int t = 0; t < TROWS; ++t) { a0[t] = 0.f; a1[t] = 0.f; a2[t] = 0.f; }

  for (int k4 = 0; k4 < 16; ++k4) {
    const float* wp = W + k4 * 4 * EMB + tid;
    float w00 = wp[0],       w01 = wp[256],         w02 = wp[512];
    float w10 = wp[EMB],     w11 = wp[EMB + 256],   w12 = wp[EMB + 512];
    float w20 = wp[2*EMB],   w21 = wp[2*EMB + 256], w22 = wp[2*EMB + 512];
    float w30 = wp[3*EMB],   w31 = wp[3*EMB + 256], w32 = wp[3*EMB + 512];
    #pragma unroll
    for (int t = 0; t < TROWS; ++t) {
      float4 p = *((const float4*)(patch + t * 64 + k4 * 4)); // wave-uniform broadcast
      a0[t] += p.x * w00; a1[t] += p.x * w01; a2[t] += p.x * w02;
      a0[t] += p.y * w10; a1[t] += p.y * w11; a2[t] += p.y * w12;
      a0[t] += p.z * w20; a1[t] += p.z * w21; a2[t] += p.z * w22;
      a0[t] += p.w * w30; a1[t] += p.w * w31; a2[t] += p.w * w32;
    }
  }

  const float pb0 = pb[tid], pb1 = pb[tid + 256], pb2 = pb[tid + 512];
  const float g0 = gmm[tid], g1 = gmm[tid + 256], g2 = gmm[tid + 512];
  const float b0 = bta[tid], b1 = bta[tid + 256], b2 = bta[tid + 512];
  const int wv = tid >> 6, ln = tid & 63;

  // --- add bias + pos-enc (keep in accumulators), LN reductions per row ---
  #pragma unroll
  for (int t = 0; t < TROWS; ++t) {
    float v0 = a0[t] + pb0 + tabg[h256[t] + tid];
    float v1 = a1[t] + pb1 + tabg[w256[t] + tid];
    float v2 = a2[t] + pb2 + tabg[d256[t] + tid];
    a0[t] = v0; a1[t] = v1; a2[t] = v2;
    float s = v0 + v1 + v2;
    float q = v0 * v0 + v1 * v1 + v2 * v2;
    #pragma unroll
    for (int off = 32; off > 0; off >>= 1) {
      s += __shfl_down(s, off, 64);
      q += __shfl_down(q, off, 64);
    }
    if (ln == 0) { wred[t][wv][0] = s; wred[t][wv][1] = q; }
  }
  __syncthreads();
  if (tid < TROWS) {
    float s = wred[tid][0][0] + wred[tid][1][0] + wred[tid][2][0] + wred[tid][3][0];
    float q = wred[tid][0][1] + wred[tid][1][1] + wred[tid][2][1] + wred[tid][3][1];
    float mean = s * (1.0f / 768.0f);
    float var = q * (1.0f / 768.0f) - mean * mean;   // biased, matches jnp.var
    rowstat[tid][0] = mean;
    rowstat[tid][1] = 1.0f / sqrtf(var + 0.001f);    // LN_EPS
  }
  __syncthreads();

  // --- normalize + store (mask rows broadcast to all 4 batches) ---
  if (isA) {
    int row0 = blk * TROWS;
    int b = row0 / UNMASKN;
    int u0 = row0 % UNMASKN;
    float* base = out + ((long)b * TOKN + u0) * EMB + tid;
    #pragma unroll
    for (int t = 0; t < TROWS; ++t) {
      float mean = rowstat[t][0], rstd = rowstat[t][1];
      float* o = base + (long)t * EMB;
      o[0]   = (a0[t] - mean) * rstd * g0 + b0;
      o[256] = (a1[t] - mean) * rstd * g1 + b1;
      o[512] = (a2[t] - mean) * rstd * g2 + b2;
    }
  } else {
    int m0 = (blk - ABLOCKS) * TROWS;
    float* base = out + ((long)UNMASKN + m0) * EMB + tid;
    #pragma unroll
    for (int t = 0; t < TROWS; ++t) {
      float mean = rowstat[t][0], rstd = rowstat[t][1];
      float o0 = (a0[t] - mean) * rstd * g0 + b0;
      float o1 = (a1[t] - mean) * rstd * g1 + b1;
      float o2 = (a2[t] - mean) * rstd * g2 + b2;
      float* o = base + (long)t * EMB;
      #pragma unroll
      for (int bb = 0; bb < NBATCH; ++bb) {
        o[0] = o0; o[256] = o1; o[512] = o2;
        o += (long)TOKN * EMB;
      }
    }
  }
}

extern "C" void kernel_launch(void* const* d_in, const int* in_sizes, int n_in,
                              void* d_out, int out_size, void* d_ws, size_t ws_size,
                              hipStream_t stream) {
  const float* x    = (const float*)d_in[0];
  const float* W    = (const float*)d_in[1];
  const float* pb   = (const float*)d_in[2];
  const float* mt   = (const float*)d_in[3];
  const float* gmm  = (const float*)d_in[4];
  const float* bta  = (const float*)d_in[5];
  const int*   perm = (const int*)d_in[6];
  float* out = (float*)d_out;
  float* out_idx = out + (long)NBATCH * TOKN * EMB;   // 42,467,328
  float* tabg = (float*)d_ws;                         // 24 KB sincos table

  setup_kernel<<<(MASKN + NTHREADS - 1) / NTHREADS, NTHREADS, 0, stream>>>(
      perm, tabg, out_idx);
  fused_embed_ln<<<ABLOCKS + BBLOCKS, NTHREADS, 0, stream>>>(
      x, W, pb, mt, gmm, bta, perm, tabg, out);
}

// Round 3
// 249.962 us; speedup vs baseline: 3.1986x; 3.1986x over previous
//
#include <hip/hip_runtime.h>
#include <math.h>

// Problem constants
#define NTHREADS 256
#define TROWS 16            // rows (tokens) per block -> 48 fp32 accumulators/thread
#define TOKN 13824          // 24*24*24
#define MASKN 10368         // 0.75 * TOKN
#define UNMASKN 3456        // TOKN - MASKN
#define EMB 768
#define NPOS 24
#define NBATCH 4
#define ABLOCKS (TOKN / TROWS)    // 864 blocks for unmask rows (4 batches * 3456 rows)
#define BBLOCKS (MASKN / TROWS)   // 648 blocks for mask rows (computed once, stored x4)
#define TABN (NPOS * 256)         // 6144 floats = 24 KB in d_ws

// Setup: build sincos pos-enc table in d_ws + write mask_idx output.
__global__ __launch_bounds__(NTHREADS) void setup_kernel(
    const int* __restrict__ perm, float* __restrict__ tabg,
    float* __restrict__ out_idx)
{
  int i = blockIdx.x * NTHREADS + threadIdx.x;
  if (i < MASKN) out_idx[i] = (float)perm[i];
  if (i < TABN) {
    // inv_freq[j] = 10000^(-j/128) = 2^(-j * log2(10000)/128)
    const float c0 = 13.287712379549449f / 128.0f;
    int pos = i >> 8, e = i & 255, j = e >> 1;
    float s = (float)pos * exp2f(-(float)j * c0);
    tabg[i] = (e & 1) ? cosf(s) : sinf(s);
  }
}

// NOTE: default launch_bounds only. Round-2 lesson: __launch_bounds__(256,4)
// clamped VGPR to 64 and spilled the 48-accumulator GEMM to scratch
// (WRITE_SIZE 166 MB -> 2.23 GB, 2.5x slower). Let the allocator be honest.
__global__ __launch_bounds__(NTHREADS) void fused_embed_ln(
    const float* __restrict__ x, const float* __restrict__ W,
    const float* __restrict__ pb, const float* __restrict__ mt,
    const float* __restrict__ gmm, const float* __restrict__ bta,
    const int* __restrict__ perm, const float* __restrict__ tabg,
    float* __restrict__ out)
{
  __shared__ __align__(16) float patch[TROWS * 64];  // 4 KB staged patch rows
  __shared__ float wred[TROWS][4][2];
  __shared__ float rowstat[TROWS][2];
  __shared__ int h256[TROWS], w256[TROWS], d256[TROWS]; // pos-enc table offsets

  const int tid = threadIdx.x;
  const int blk = blockIdx.x;
  const bool isA = blk < ABLOCKS;

  // --- token indices + decomposed positions for this block's rows ---
  if (tid < TROWS) {
    int r;
    if (isA) {
      int row0 = blk * TROWS;            // global unmask row in [0, 13824)
      int u = row0 % UNMASKN + tid;      // 3456 % 16 == 0 -> block stays in one batch
      r = perm[MASKN + u];               // unmask_idx[u]
    } else {
      int m0 = (blk - ABLOCKS) * TROWS;
      r = perm[m0 + tid];                // mask_idx[m]
    }
    int h = r / 576; int rem = r - h * 576;
    int w = rem / 24; int d = rem - w * 24;
    h256[tid] = h << 8; w256[tid] = w << 8; d256[tid] = d << 8;
  }
  __syncthreads();

  // --- stage 16 patch rows (64 floats each) into LDS ---
  if (isA) {
    int b = (blk * TROWS) / UNMASKN;
    int t = tid >> 4, seg = tid & 15;    // seg = ph*4 + pw; float4 covers pd 0..3
    int h = h256[t] >> 8, w = w256[t] >> 8, d = d256[t] >> 8;
    int ph = seg >> 2, pw = seg & 3;
    const float4* src = (const float4*)(x +
        ((((long)b * 96 + h * 4 + ph) * 96 + (w * 4 + pw)) * 96 + d * 4));
    ((float4*)patch)[tid] = *src;
  } else {
    int m0 = (blk - ABLOCKS) * TROWS;
    const float4* src = (const float4*)(mt + (long)m0 * 64);
    ((float4*)patch)[tid] = src[tid];
  }
  __syncthreads();

  // --- GEMM: each thread accumulates columns {tid, tid+256, tid+512} for 16 rows ---
  float a0[TROWS], a1[TROWS], a2[TROWS];
  #pragma unroll
  for (int t = 0; t < TROWS; ++t) { a0[t] = 0.f; a1[t] = 0.f; a2[t] = 0.f; }

  for (int k4 = 0; k4 < 16; ++k4) {
    const float* wp = W + k4 * 4 * EMB + tid;
    float w00 = wp[0],       w01 = wp[256],         w02 = wp[512];
    float w10 = wp[EMB],     w11 = wp[EMB + 256],   w12 = wp[EMB + 512];
    float w20 = wp[2*EMB],   w21 = wp[2*EMB + 256], w22 = wp[2*EMB + 512];
    float w30 = wp[3*EMB],   w31 = wp[3*EMB + 256], w32 = wp[3*EMB + 512];
    #pragma unroll
    for (int t = 0; t < TROWS; ++t) {
      float4 p = *((const float4*)(patch + t * 64 + k4 * 4)); // wave-uniform broadcast
      a0[t] += p.x * w00; a1[t] += p.x * w01; a2[t] += p.x * w02;
      a0[t] += p.y * w10; a1[t] += p.y * w11; a2[t] += p.y * w12;
      a0[t] += p.z * w20; a1[t] += p.z * w21; a2[t] += p.z * w22;
      a0[t] += p.w * w30; a1[t] += p.w * w31; a2[t] += p.w * w32;
    }
  }

  const float pb0 = pb[tid], pb1 = pb[tid + 256], pb2 = pb[tid + 512];
  const float g0 = gmm[tid], g1 = gmm[tid + 256], g2 = gmm[tid + 512];
  const float b0 = bta[tid], b1 = bta[tid + 256], b2 = bta[tid + 512];
  const int wv = tid >> 6, ln = tid & 63;

  // --- add bias + pos-enc (keep in accumulators), LN reductions per row ---
  #pragma unroll
  for (int t = 0; t < TROWS; ++t) {
    float v0 = a0[t] + pb0 + tabg[h256[t] + tid];
    float v1 = a1[t] + pb1 + tabg[w256[t] + tid];
    float v2 = a2[t] + pb2 + tabg[d256[t] + tid];
    a0[t] = v0; a1[t] = v1; a2[t] = v2;
    float s = v0 + v1 + v2;
    float q = v0 * v0 + v1 * v1 + v2 * v2;
    #pragma unroll
    for (int off = 32; off > 0; off >>= 1) {
      s += __shfl_down(s, off, 64);
      q += __shfl_down(q, off, 64);
    }
    if (ln == 0) { wred[t][wv][0] = s; wred[t][wv][1] = q; }
  }
  __syncthreads();
  if (tid < TROWS) {
    float s = wred[tid][0][0] + wred[tid][1][0] + wred[tid][2][0] + wred[tid][3][0];
    float q = wred[tid][0][1] + wred[tid][1][1] + wred[tid][2][1] + wred[tid][3][1];
    float mean = s * (1.0f / 768.0f);
    float var = q * (1.0f / 768.0f) - mean * mean;   // biased, matches jnp.var
    rowstat[tid][0] = mean;
    rowstat[tid][1] = 1.0f / sqrtf(var + 0.001f);    // LN_EPS
  }
  __syncthreads();

  // --- normalize + store (mask rows broadcast to all 4 batches) ---
  if (isA) {
    int row0 = blk * TROWS;
    int b = row0 / UNMASKN;
    int u0 = row0 % UNMASKN;
    float* base = out + ((long)b * TOKN + u0) * EMB + tid;
    #pragma unroll
    for (int t = 0; t < TROWS; ++t) {
      float mean = rowstat[t][0], rstd = rowstat[t][1];
      float* o = base + (long)t * EMB;
      o[0]   = (a0[t] - mean) * rstd * g0 + b0;
      o[256] = (a1[t] - mean) * rstd * g1 + b1;
      o[512] = (a2[t] - mean) * rstd * g2 + b2;
    }
  } else {
    int m0 = (blk - ABLOCKS) * TROWS;
    float* base = out + ((long)UNMASKN + m0) * EMB + tid;
    #pragma unroll
    for (int t = 0; t < TROWS; ++t) {
      float mean = rowstat[t][0], rstd = rowstat[t][1];
      float o0 = (a0[t] - mean) * rstd * g0 + b0;
      float o1 = (a1[t] - mean) * rstd * g1 + b1;
      float o2 = (a2[t] - mean) * rstd * g2 + b2;
      float* o = base + (long)t * EMB;
      #pragma unroll
      for (int bb = 0; bb < NBATCH; ++bb) {
        o[0] = o0; o[256] = o1; o[512] = o2;
        o += (long)TOKN * EMB;
      }
    }
  }
}

extern "C" void kernel_launch(void* const* d_in, const int* in_sizes, int n_in,
                              void* d_out, int out_size, void* d_ws, size_t ws_size,
                              hipStream_t stream) {
  const float* x    = (const float*)d_in[0];
  const float* W    = (const float*)d_in[1];
  const float* pb   = (const float*)d_in[2];
  const float* mt   = (const float*)d_in[3];
  const float* gmm  = (const float*)d_in[4];
  const float* bta  = (const float*)d_in[5];
  const int*   perm = (const int*)d_in[6];
  float* out = (float*)d_out;
  float* out_idx = out + (long)NBATCH * TOKN * EMB;   // 42,467,328
  float* tabg = (float*)d_ws;                         // 24 KB sincos table

  setup_kernel<<<(MASKN + NTHREADS - 1) / NTHREADS, NTHREADS, 0, stream>>>(
      perm, tabg, out_idx);
  fused_embed_ln<<<ABLOCKS + BBLOCKS, NTHREADS, 0, stream>>>(
      x, W, pb, mt, gmm, bta, perm, tabg, out);
}

// Round 4
// 214.240 us; speedup vs baseline: 3.7319x; 1.1667x over previous
//
#include <hip/hip_runtime.h>
#include <math.h>

// Problem constants
#define NTHREADS 256
#define TROWS 16            // rows (tokens) per block = one 16-row MFMA tile
#define TOKN 13824          // 24*24*24
#define MASKN 10368         // 0.75 * TOKN
#define UNMASKN 3456        // TOKN - MASKN
#define EMB 768
#define NPOS 24
#define NBATCH 4
#define ABLOCKS (TOKN / TROWS)    // 864 blocks (4 batches * 3456 unmask rows)
#define BBLOCKS (MASKN / TROWS)   // 648 blocks (mask rows, computed once, stored x4)
#define TABN (NPOS * 256)         // 6144 floats = 24 KB sincos table in d_ws
#define WN (64 * EMB)             // 49152 W elements

typedef __attribute__((ext_vector_type(8))) short short8;   // 8 bf16 = 4 VGPRs
typedef __attribute__((ext_vector_type(4))) float f32x4;

__device__ __forceinline__ short f2bf(float f) {
  union { float f; unsigned u; } c; c.f = f;
  unsigned u = c.u + 0x7FFFu + ((c.u >> 16) & 1u);   // RNE
  return (short)(u >> 16);
}

// Setup: sincos table + bf16-transposed W (wsW[col][k]) in d_ws + mask_idx out.
__global__ __launch_bounds__(NTHREADS) void setup_kernel(
    const float* __restrict__ W, const int* __restrict__ perm,
    float* __restrict__ tabg, short* __restrict__ wsW,
    float* __restrict__ out_idx)
{
  int i = blockIdx.x * NTHREADS + threadIdx.x;
  if (i < MASKN) out_idx[i] = (float)perm[i];
  if (i < TABN) {
    // inv_freq[j] = 10000^(-j/128) = 2^(-j * log2(10000)/128)
    const float c0 = 13.287712379549449f / 128.0f;
    int pos = i >> 8, e = i & 255, j = e >> 1;
    float s = (float)pos * exp2f(-(float)j * c0);
    tabg[i] = (e & 1) ? cosf(s) : sinf(s);
  }
  if (i < WN) {
    int col = i >> 6, k = i & 63;
    wsW[i] = f2bf(W[k * EMB + col]);   // wsW[col*64 + k]
  }
}

// NOTE: default launch_bounds only. Round-2 lesson: a min-waves clamp forced
// VGPR=64 and spilled the accumulators to scratch (2.2 GB of writes).
__global__ __launch_bounds__(NTHREADS) void fused_embed_ln_mfma(
    const float* __restrict__ x, const float* __restrict__ pb,
    const float* __restrict__ mt, const float* __restrict__ gmm,
    const float* __restrict__ bta, const int* __restrict__ perm,
    const float* __restrict__ tabg, const short* __restrict__ wsW,
    float* __restrict__ out)
{
  __shared__ __align__(16) short aLds[TROWS][72];  // bf16 A, +8 pad (2.3 KB)
  __shared__ int segbase[3][TROWS];                // h/w/d << 8 per row
  __shared__ float wred[TROWS][4][2];
  __shared__ float rowstat[TROWS][2];

  const int tid = threadIdx.x;
  const int blk = blockIdx.x;
  const bool isA = blk < ABLOCKS;

  // --- token indices + decomposed positions ---
  if (tid < TROWS) {
    int r;
    if (isA) {
      int u = (blk * TROWS) % UNMASKN + tid;  // 3456 % 16 == 0: one batch/block
      r = perm[MASKN + u];
    } else {
      r = perm[(blk - ABLOCKS) * TROWS + tid];
    }
    int h = r / 576; int rem = r - h * 576;
    int w = rem / 24; int d = rem - w * 24;
    segbase[0][tid] = h << 8; segbase[1][tid] = w << 8; segbase[2][tid] = d << 8;
  }
  __syncthreads();

  // --- stage 16 patch rows into LDS as bf16 ---
  {
    int t = tid >> 4, seg = tid & 15;
    float4 v;
    if (isA) {
      int b = (blk * TROWS) / UNMASKN;
      int h = segbase[0][t] >> 8, w = segbase[1][t] >> 8, d = segbase[2][t] >> 8;
      int ph = seg >> 2, pw = seg & 3;
      v = *(const float4*)(x +
          ((((long)b * 96 + h * 4 + ph) * 96 + (w * 4 + pw)) * 96 + d * 4));
    } else {
      int m0 = (blk - ABLOCKS) * TROWS;
      v = *(const float4*)(mt + (long)(m0 + t) * 64 + seg * 4);
    }
    short4 s4; s4.x = f2bf(v.x); s4.y = f2bf(v.y); s4.z = f2bf(v.z); s4.w = f2bf(v.w);
    *(short4*)&aLds[t][seg * 4] = s4;
  }
  __syncthreads();

  // --- MFMA GEMM: wave wv covers cols [wv*192, wv*192+192) = 12 tiles ---
  const int wv = tid >> 6, lane = tid & 63;
  const int n16 = lane & 15, q = lane >> 4;
  const int colbase = wv * 192;

  // A frags: A[m=lane&15][k=quad*8+j], chunks k=0..31 and 32..63
  short8 af0 = *(const short8*)&aLds[n16][q * 8];
  short8 af1 = *(const short8*)&aLds[n16][32 + q * 8];

  f32x4 acc[12];
  const short* wp = wsW + (colbase + n16) * 64 + q * 8;
  #pragma unroll
  for (int jt = 0; jt < 12; ++jt) {
    short8 bf0 = *(const short8*)(wp + jt * 16 * 64);
    short8 bf1 = *(const short8*)(wp + jt * 16 * 64 + 32);
    f32x4 c = {0.f, 0.f, 0.f, 0.f};
    c = __builtin_amdgcn_mfma_f32_16x16x32_bf16(af0, bf0, c, 0, 0, 0);
    c = __builtin_amdgcn_mfma_f32_16x16x32_bf16(af1, bf1, c, 0, 0, 0);
    acc[jt] = c;
  }

  // --- add bias + pos-enc, per-row LN stats ---
  // C/D layout: col = lane&15 (tile-local), row = q*4 + reg
  float s[4] = {0.f, 0.f, 0.f, 0.f}, qq[4] = {0.f, 0.f, 0.f, 0.f};
  #pragma unroll
  for (int jt = 0; jt < 12; ++jt) {
    int colb = colbase + jt * 16;
    int seg = colb >> 8;                 // uniform per (wv,jt): tile never crosses 256
    int cb = (colb & 255) + n16;
    float pbj = pb[colb + n16];
    #pragma unroll
    for (int r = 0; r < 4; ++r) {
      float v = acc[jt][r] + pbj + tabg[segbase[seg][q * 4 + r] + cb];
      acc[jt][r] = v;
      s[r] += v; qq[r] += v * v;
    }
  }
  #pragma unroll
  for (int r = 0; r < 4; ++r) {
    #pragma unroll
    for (int m = 8; m >= 1; m >>= 1) {
      s[r]  += __shfl_xor(s[r],  m, 16);
      qq[r] += __shfl_xor(qq[r], m, 16);
    }
  }
  if (n16 == 0) {
    #pragma unroll
    for (int r = 0; r < 4; ++r) {
      wred[q * 4 + r][wv][0] = s[r];
      wred[q * 4 + r][wv][1] = qq[r];
    }
  }
  __syncthreads();
  if (tid < TROWS) {
    float ss = wred[tid][0][0] + wred[tid][1][0] + wred[tid][2][0] + wred[tid][3][0];
    float qs = wred[tid][0][1] + wred[tid][1][1] + wred[tid][2][1] + wred[tid][3][1];
    float mean = ss * (1.0f / 768.0f);
    float var = qs * (1.0f / 768.0f) - mean * mean;   // biased, matches jnp.var
    rowstat[tid][0] = mean;
    rowstat[tid][1] = 1.0f / sqrtf(var + 0.001f);     // LN_EPS
  }
  __syncthreads();

  float mr[4], rr[4];
  #pragma unroll
  for (int r = 0; r < 4; ++r) {
    mr[r] = rowstat[q * 4 + r][0];
    rr[r] = rowstat[q * 4 + r][1];
  }

  // --- normalize + store (mask rows broadcast to all 4 batches) ---
  if (isA) {
    int row0 = blk * TROWS;
    int b = row0 / UNMASKN;
    int u0 = row0 % UNMASKN;
    float* base = out + ((long)b * TOKN + u0 + q * 4) * EMB + colbase + n16;
    #pragma unroll
    for (int jt = 0; jt < 12; ++jt) {
      int col = colbase + jt * 16 + n16;
      float g = gmm[col], bb = bta[col];
      #pragma unroll
      for (int r = 0; r < 4; ++r)
        base[(long)r * EMB + jt * 16] = (acc[jt][r] - mr[r]) * rr[r] * g + bb;
    }
  } else {
    int m0 = (blk - ABLOCKS) * TROWS;
    float* base = out + ((long)UNMASKN + m0 + q * 4) * EMB + colbase + n16;
    #pragma unroll
    for (int jt = 0; jt < 12; ++jt) {
      int col = colbase + jt * 16 + n16;
      float g = gmm[col], bb = bta[col];
      #pragma unroll
      for (int r = 0; r < 4; ++r) {
        float o = (acc[jt][r] - mr[r]) * rr[r] * g + bb;
        float* p = base + (long)r * EMB + jt * 16;
        #pragma unroll
        for (int b4 = 0; b4 < NBATCH; ++b4) { *p = o; p += (long)TOKN * EMB; }
      }
    }
  }
}

extern "C" void kernel_launch(void* const* d_in, const int* in_sizes, int n_in,
                              void* d_out, int out_size, void* d_ws, size_t ws_size,
                              hipStream_t stream) {
  const float* x    = (const float*)d_in[0];
  const float* W    = (const float*)d_in[1];
  const float* pb   = (const float*)d_in[2];
  const float* mt   = (const float*)d_in[3];
  const float* gmm  = (const float*)d_in[4];
  const float* bta  = (const float*)d_in[5];
  const int*   perm = (const int*)d_in[6];
  float* out = (float*)d_out;
  float* out_idx = out + (long)NBATCH * TOKN * EMB;   // 42,467,328

  float* tabg = (float*)d_ws;                         // 24 KB sincos table
  short* wsW  = (short*)((char*)d_ws + TABN * 4);     // 96 KB bf16 W^T [col][k]

  setup_kernel<<<(WN + NTHREADS - 1) / NTHREADS, NTHREADS, 0, stream>>>(
      W, perm, tabg, wsW, out_idx);
  fused_embed_ln_mfma<<<ABLOCKS + BBLOCKS, NTHREADS, 0, stream>>>(
      x, pb, mt, gmm, bta, perm, tabg, wsW, out);
}